// Round 10
// baseline (2731.562 us; speedup 1.0000x reference)
//
#include <hip/hip_runtime.h>
#include <math.h>

// Elman RNN, two-phase.
//   Phase 1 (parallel): z = x*W1^T + b1 + b2, f32-exact (3-product hi/lo
//     bf16 MFMA), stored in MFMA C-fragment order INTO the h_seq region of
//     d_out. Slab (s,tile)*2048 floats == bytes of h_seq(s, rows 16*tile..+16);
//     ONE recur block owns the whole slab (reads z(s) 2 steps before writing
//     h_seq(s)) -> self-aliasing only, no cross-block hazard (r8 lesson).
//   Phase 2 (serial, 32 blocks x 4 waves, M=16, N=32/wave):
//     h_t = tanh(h_{t-1}*W2^T + z_t).
//     R7/R9 PIPE ACCOUNTING: per-wave A-ingest is fixed (128B/lane), so LDS
//     reads = 8 b128 x waves/CU: r7's 8 waves = 768 cyc/step (saturated);
//     4 waves x N=32 halves that to 384. r9 showed 1 wave/SIMD + BARRIER
//     exposes the full serial chain (~+450 cyc) -> replace the barrier with
//     PER-WAVE FLAG SYNC: chunk c of h is produced exactly by wave c; poll
//     fl[c] >= s-1 just before reading chunk c (own chunk free). Flag written
//     after lgkmcnt(0). Double-buffer safe: W observes all flags >= s-1
//     before its writes => every wave's step-(s-1) reads of the plane being
//     overwritten are complete. No arrival-wait; epilogue/stores overlap.
//     Chunk order rotated per wave (own chunk first); weights loaded
//     PRE-ROTATED so all register arrays are statically indexed (rule #20).
//     R5 LESSON (unchanged): per-step h error must stay ~1e-6 -> trunc
//     hi/lo splits + 3 products: W2hi*h_hi + W2lo*h_hi + W2hi*h_lo.

#define S_LEN 2048
#define B_SZ  512
#define I_SZ  64
#define H_SZ  128
#define NTILE 32                   // 16-row slabs per step
#define BLK1  512
#define BLK2  256                  // 4 waves
#define SPB   8                    // prepass: steps per block
#define SBH   (B_SZ * H_SZ)        // floats per step-slab in out (65536)

typedef short bf16x8 __attribute__((ext_vector_type(8)));
typedef float f32x4  __attribute__((ext_vector_type(4)));

#define MFMA(A, B, C) __builtin_amdgcn_mfma_f32_16x16x32_bf16((A), (B), (C), 0, 0, 0)

__device__ __forceinline__ unsigned fbits(float v) {
    union { float f; unsigned u; } x; x.f = v; return x.u;
}
__device__ __forceinline__ float fval(unsigned u) {
    union { float f; unsigned u; } x; x.u = u; return x.f;
}
__device__ __forceinline__ unsigned short bf_trunc(float v) {
    return (unsigned short)(fbits(v) >> 16);
}
// split 8 consecutive floats into hi/lo bf16 fragments (trunc, r4-proven)
__device__ __forceinline__ void split8t(float4 a, float4 b, bf16x8* hi, bf16x8* lo) {
    float v[8] = {a.x, a.y, a.z, a.w, b.x, b.y, b.z, b.w};
    #pragma unroll
    for (int j = 0; j < 8; ++j) {
        unsigned short h = bf_trunc(v[j]);
        (*hi)[j] = (short)h;
        (*lo)[j] = (short)bf_trunc(v[j] - fval(((unsigned)h) << 16));
    }
}

// ---------------- Phase 1: z = x*W1^T + b1 + b2 (fragment layout) ----------
__global__ __launch_bounds__(BLK1) void rnn_prepass(
    const float* __restrict__ x,
    const float* __restrict__ W1,
    const float* __restrict__ b1,
    const float* __restrict__ b2,
    float* __restrict__ z)
{
    const int tid  = threadIdx.x;
    const int lane = tid & 63;
    const int w    = tid >> 6;
    const int l15  = lane & 15;
    const int l4   = lane >> 4;
    const int unit = (w << 4) + l15;
    const int bid  = blockIdx.x;
    const int tile = bid & (NTILE - 1);
    const int s0   = (bid >> 5) * SPB;
    const int b0   = tile << 4;

    bf16x8 w1h[2], w1l[2];
    #pragma unroll
    for (int c = 0; c < 2; ++c) {
        const float* wr = W1 + unit * I_SZ + 32 * c + l4 * 8;
        split8t(*(const float4*)wr, *(const float4*)(wr + 4), &w1h[c], &w1l[c]);
    }
    const float zb = b1[unit] + b2[unit];

    for (int i = 0; i < SPB; ++i) {
        const int s = s0 + i;
        const float* xr = x + ((size_t)s * B_SZ + b0 + l15) * I_SZ + l4 * 8;
        bf16x8 xh[2], xl[2];
        #pragma unroll
        for (int c = 0; c < 2; ++c)
            split8t(*(const float4*)(xr + 32 * c), *(const float4*)(xr + 32 * c + 4),
                    &xh[c], &xl[c]);

        f32x4 acc  = {zb, zb, zb, zb};
        f32x4 acc2 = {0.f, 0.f, 0.f, 0.f};
        acc  = MFMA(xh[0], w1h[0], acc);   acc  = MFMA(xh[1], w1h[1], acc);
        acc2 = MFMA(xl[0], w1h[0], acc2);  acc2 = MFMA(xl[1], w1h[1], acc2);
        acc2 = MFMA(xh[0], w1l[0], acc2);  acc2 = MFMA(xh[1], w1l[1], acc2);
        acc += acc2;

        // subtile w of slab (s,tile): 1 KiB per wave, matches recur zp
        *(f32x4*)(z + ((size_t)(s * NTILE + tile) * 8 + w) * 256 + lane * 4) = acc;
    }
}

// ---- Phase 2: serial recurrence (32 blocks, M=16, 4 waves, N=32, flags) ---
__global__ __launch_bounds__(BLK2, 1) void rnn_recur(
    const float* __restrict__ W2,
    const float* zr,              // z region (fragment layout), aliases out
    float* out)
{
    const int tid  = threadIdx.x;
    const int lane = tid & 63;
    const int W    = tid >> 6;        // wave 0..3 -> units [32W, 32W+32)
    const int l15  = lane & 15;
    const int l4   = lane >> 4;
    const int tile = blockIdx.x;
    const int b0   = tile << 4;

    __shared__ short hp_hi[2][16 * H_SZ];   // 2 x 4 KiB, XOR-swizzled
    __shared__ short hp_lo[2][16 * H_SZ];
    __shared__ int   fl[4];                 // per-wave progress flags

    // W2 B-fragments hi/lo, PRE-ROTATED chunk order: slot i = chunk (W+i)&3
    bf16x8 w2h[2][4], w2l[2][4];
    #pragma unroll
    for (int st = 0; st < 2; ++st) {
        const int n = (W << 5) + (st << 4) + l15;
        #pragma unroll
        for (int i = 0; i < 4; ++i) {
            const int cc = (W + i) & 3;
            const float* wr = W2 + n * H_SZ + 32 * cc + l4 * 8;
            split8t(*(const float4*)wr, *(const float4*)(wr + 4),
                    &w2h[st][i], &w2l[st][i]);
        }
    }

    // LDS read offsets (rotated chunk order), swizzle: byte ^= (row&7)<<4
    int hro_i[4];
    #pragma unroll
    for (int i = 0; i < 4; ++i) {
        const int cc = (W + i) & 3;
        hro_i[i] = l15 * 256 + (((cc << 6) + (l4 << 4)) ^ ((l15 & 7) << 4));
    }
    // write offsets: subtile st, reg r -> row 4*l4+r, unit 32W+16st+l15
    int woh[2][4];
    #pragma unroll
    for (int st = 0; st < 2; ++st)
        #pragma unroll
        for (int r = 0; r < 4; ++r) {
            int row = (l4 << 2) + r;
            woh[st][r] = row * 256 +
                ((((W << 5) + (st << 4) + l15) * 2) ^ ((row & 7) << 4));
        }

    // z pointers: subtiles 2W, 2W+1 of this block's slab
    const float* zp0 = zr + (size_t)tile * 2048 + (size_t)(2 * W) * 256 + lane * 4;
    const float* zp1 = zp0 + 256;
    // h_seq pointers: row b0+4*l4 (+r), col 32W (+16*st) + l15
    float* po0 = out + (size_t)(b0 + (l4 << 2)) * H_SZ + (W << 5) + l15;
    float* po1 = po0 + 16;

    if (tid < 4) fl[tid] = -1;
    __syncthreads();
    volatile int* vfl = fl;

    // prologue: z(0), z(1) in flight
    f32x4 zA0 = *(const f32x4*)(zp0);
    f32x4 zA1 = *(const f32x4*)(zp1);
    f32x4 zB0 = *(const f32x4*)(zp0 + SBH);
    f32x4 zB1 = *(const f32x4*)(zp1 + SBH);

    float tl0[4], tl1[4];

#define EPILOGUE(S, PW, A0, A1)                                               \
{                                                                             \
    _Pragma("unroll")                                                         \
    for (int r = 0; r < 4; ++r) {                                             \
        float u0 = 1.0f - 2.0f * __builtin_amdgcn_rcpf(1.0f + __expf(2.0f*(A0)[r])); \
        float u1 = 1.0f - 2.0f * __builtin_amdgcn_rcpf(1.0f + __expf(2.0f*(A1)[r])); \
        tl0[r] = u0;  tl1[r] = u1;                                            \
        unsigned short h0 = bf_trunc(u0), h1 = bf_trunc(u1);                  \
        *(short*)((char*)hp_hi[PW] + woh[0][r]) = (short)h0;                  \
        *(short*)((char*)hp_lo[PW] + woh[0][r]) =                             \
            (short)bf_trunc(u0 - fval(((unsigned)h0) << 16));                 \
        *(short*)((char*)hp_hi[PW] + woh[1][r]) = (short)h1;                  \
        *(short*)((char*)hp_lo[PW] + woh[1][r]) =                             \
            (short)bf_trunc(u1 - fval(((unsigned)h1) << 16));                 \
    }                                                                         \
    asm volatile("s_waitcnt lgkmcnt(0)" ::: "memory");                        \
    if (lane == 0) vfl[W] = (S);                                              \
    asm volatile("" ::: "memory");                                            \
    _Pragma("unroll")                                                         \
    for (int r = 0; r < 4; ++r) {                                             \
        po0[(size_t)(S) * SBH + (size_t)r * H_SZ] = tl0[r];                   \
        po1[(size_t)(S) * SBH + (size_t)r * H_SZ] = tl1[r];                   \
    }                                                                         \
}

#define RSTEP(S, ZQ0, ZQ1)                                                    \
{                                                                             \
    const int t  = (S) - 1;                                                   \
    const int pr = t & 1;                                                     \
    f32x4 a0 = ZQ0, a1 = ZQ1;                                                 \
    f32x4 b0v = {0.f,0.f,0.f,0.f}, b1v = b0v, c0v = b0v, c1v = b0v;           \
    { int sp = (S) + 2; if (sp > S_LEN - 1) sp = S_LEN - 1;                   \
      ZQ0 = *(const f32x4*)(zp0 + (size_t)sp * SBH);                          \
      ZQ1 = *(const f32x4*)(zp1 + (size_t)sp * SBH); }                        \
    _Pragma("unroll")                                                         \
    for (int i = 0; i < 4; ++i) {                                             \
        if (i != 0) {                                                         \
            const int cc = (W + i) & 3;                                       \
            while (vfl[cc] < t) __builtin_amdgcn_s_sleep(1);                  \
            asm volatile("" ::: "memory");                                    \
        }                                                                     \
        bf16x8 ah = *(const bf16x8*)((const char*)hp_hi[pr] + hro_i[i]);      \
        bf16x8 al = *(const bf16x8*)((const char*)hp_lo[pr] + hro_i[i]);      \
        a0  = MFMA(ah, w2h[0][i], a0);   a1  = MFMA(ah, w2h[1][i], a1);       \
        b0v = MFMA(al, w2h[0][i], b0v);  b1v = MFMA(al, w2h[1][i], b1v);      \
        c0v = MFMA(ah, w2l[0][i], c0v);  c1v = MFMA(ah, w2l[1][i], c1v);      \
    }                                                                         \
    a0 = (a0 + b0v) + c0v;  a1 = (a1 + b1v) + c1v;                            \
    EPILOGUE((S), (S) & 1, a0, a1)                                            \
}

    // ---- step 0: h0 = 0 -> h1... no, h_1 = tanh(z_0) (no W2 term) ----
    {
        f32x4 a0 = zA0, a1 = zA1;
        zA0 = *(const f32x4*)(zp0 + (size_t)2 * SBH);   // prefetch z(2)
        zA1 = *(const f32x4*)(zp1 + (size_t)2 * SBH);
        EPILOGUE(0, 0, a0, a1)
    }

    // ---- steps 1..2046 in pairs, then 2047 ----
    for (int s = 1; s < S_LEN - 1; s += 2) {
        RSTEP(s,     zB0, zB1);
        RSTEP(s + 1, zA0, zA1);
    }
    RSTEP(S_LEN - 1, zB0, zB1);

#undef RSTEP
#undef EPILOGUE

    // h_last (step S_LEN-1 values held in tl)
    #pragma unroll
    for (int r = 0; r < 4; ++r) {
        po0[(size_t)S_LEN * SBH + (size_t)r * H_SZ] = tl0[r];
        po1[(size_t)S_LEN * SBH + (size_t)r * H_SZ] = tl1[r];
    }
}

extern "C" void kernel_launch(void* const* d_in, const int* in_sizes, int n_in,
                              void* d_out, int out_size, void* d_ws, size_t ws_size,
                              hipStream_t stream) {
    const float* x  = (const float*)d_in[0];
    const float* W1 = (const float*)d_in[1];
    const float* b1 = (const float*)d_in[2];
    const float* W2 = (const float*)d_in[3];
    const float* b2 = (const float*)d_in[4];
    float* out = (float*)d_out;

    rnn_prepass<<<dim3((S_LEN / SPB) * NTILE), dim3(BLK1), 0, stream>>>(x, W1, b1, b2, out);
    rnn_recur<<<dim3(NTILE), dim3(BLK2), 0, stream>>>(W2, out, out);
}